// Round 4
// baseline (333.258 us; speedup 1.0000x reference)
//
#include <hip/hip_runtime.h>
#include <math.h>

// Problem: B=32, T=512, F=64, O=64.
// delta[b,t,f] = (t==0) ? 0 : in[b,t,f]-in[b,t-1,f]
// x = (delta - bn_mean) * (bn_w * rsqrt(bn_var+1e-5)) + bn_b
// enc_o = x * enc_w[o] + enc_b[o]
// LIF scan over o: h = v + (enc_o - v)/2 ; s = (h>=1) ; v = s?0:h
// out[b,o,f,t] = s   (fp32, 0/1)
//
// R8 = DIAGNOSTIC ROUND. Four schedule variants (NT stores, 2x occupancy,
// 4x run length, XCD swizzles) all landed at dur_us 271-282: the store
// path appears schedule-INVARIANT, but the kernel's own counters have
// never been visible (top-5 saturated by ~163us harness fills). This
// kernel is arithmetically IDENTICAL per element (absmax must stay 0)
// but runs on 32 fat blocks (one per b, serial loop over 8 f-octets) so
// it is ~3-4x slower and surfaces as the TOP dispatch with its own
// FETCH_SIZE / WRITE_SIZE / VALUBusy row.
//
// Decision matrix (pre-committed):
//  - WRITE~256MiB, FETCH~4-40MB  -> true DRAM-side cap; attack layout.
//  - FETCH >~250MB               -> read-for-ownership smoking gun;
//                                   fix full-line store detection.
//  - dur_total - dur_kernel >> 165us -> hidden harness dispatches;
//                                   kernel closer to roofline than assumed.

#define B_DIM 32
#define T_DIM 512
#define F_DIM 64
#define O_DIM 64

typedef float v4f __attribute__((ext_vector_type(4)));

__global__ __launch_bounds__(1024) void delta_lif_kernel(
    const float* __restrict__ in,     // [B,T,F]
    const float* __restrict__ enc_w,  // [64] (O,1)
    const float* __restrict__ enc_b,  // [64]
    const float* __restrict__ bn_w,   // [1]
    const float* __restrict__ bn_b,   // [1]
    const float* __restrict__ bn_mean,// [1]
    const float* __restrict__ bn_var, // [1]
    float* __restrict__ out)          // [B,O,F,T]
{
#pragma clang fp contract(off)
    // BatchNorm scalars — replicate reference op order exactly.
    const float vpe  = bn_var[0] + 1e-5f;
    const float r    = (float)(1.0 / sqrt((double)vpe));
    const float inv  = bn_w[0] * r;
    const float mean = bn_mean[0];
    const float bnb  = bn_b[0];

    const int b  = blockIdx.x;        // 0..31: one block per batch b
    const int lt = threadIdx.x;       // 0..1023
    const int fsub = lt >> 7;         // 0..7
    const int t0   = (lt & 127) << 2; // 0..508

    // Serial loop over the 8 f-octets this block owns.
    for (int oct = 0; oct < 8; ++oct) {
        const int f = (oct << 3) + fsub;

        // input: in[b, t, f] = in[b*T*F + t*F + f]
        const float* pin = in + b * (T_DIM * F_DIM) + f;
        const float c0 = pin[(t0 + 0) * F_DIM];
        const float c1 = pin[(t0 + 1) * F_DIM];
        const float c2 = pin[(t0 + 2) * F_DIM];
        const float c3 = pin[(t0 + 3) * F_DIM];
        const float p  = (t0 == 0) ? c0 : pin[(t0 - 1) * F_DIM];

        const float x0 = ((c0 - p)  - mean) * inv + bnb;
        const float x1 = ((c1 - c0) - mean) * inv + bnb;
        const float x2 = ((c2 - c1) - mean) * inv + bnb;
        const float x3 = ((c3 - c2) - mean) * inv + bnb;

        float v0 = 0.0f, v1 = 0.0f, v2 = 0.0f, v3 = 0.0f;

        // out[b,o,f,t] = out[(b<<21) + (o<<15) + (f<<9) + t]
        float* pout = out + (b << 21) + (f << 9) + t0;

#pragma unroll 8
        for (int o = 0; o < O_DIM; ++o) {
            const float w  = enc_w[o];
            const float bb = enc_b[o];

            const float e0 = x0 * w + bb;
            const float e1 = x1 * w + bb;
            const float e2 = x2 * w + bb;
            const float e3 = x3 * w + bb;

            // h = v + (e - v)/2 ; /2 exact -> *0.5f identical
            const float h0 = v0 + (e0 - v0) * 0.5f;
            const float h1 = v1 + (e1 - v1) * 0.5f;
            const float h2 = v2 + (e2 - v2) * 0.5f;
            const float h3 = v3 + (e3 - v3) * 0.5f;

            const bool g0 = (h0 >= 1.0f);
            const bool g1 = (h1 >= 1.0f);
            const bool g2 = (h2 >= 1.0f);
            const bool g3 = (h3 >= 1.0f);

            v4f s;
            s.x = g0 ? 1.0f : 0.0f;
            s.y = g1 ? 1.0f : 0.0f;
            s.z = g2 ? 1.0f : 0.0f;
            s.w = g3 ? 1.0f : 0.0f;

            v0 = g0 ? 0.0f : h0;
            v1 = g1 ? 0.0f : h1;
            v2 = g2 ? 0.0f : h2;
            v3 = g3 ? 0.0f : h3;

            *(v4f*)(pout + (o << 15)) = s;
        }
    }
}

extern "C" void kernel_launch(void* const* d_in, const int* in_sizes, int n_in,
                              void* d_out, int out_size, void* d_ws, size_t ws_size,
                              hipStream_t stream) {
    const float* in      = (const float*)d_in[0];
    const float* enc_w   = (const float*)d_in[1];
    const float* enc_b   = (const float*)d_in[2];
    const float* bn_w    = (const float*)d_in[3];
    const float* bn_b    = (const float*)d_in[4];
    const float* bn_mean = (const float*)d_in[5];
    const float* bn_var  = (const float*)d_in[6];
    float* out = (float*)d_out;

    // DIAGNOSTIC: 32 blocks (one per b) x 1024 threads — deliberately
    // slow so the kernel surfaces in the top-5 counter table.
    delta_lif_kernel<<<dim3(32), dim3(1024), 0, stream>>>(
        in, enc_w, enc_b, bn_w, bn_b, bn_mean, bn_var, out);
}

// Round 5
// 309.313 us; speedup vs baseline: 1.0774x; 1.0774x over previous
//
#include <hip/hip_runtime.h>
#include <math.h>

// Problem: B=32, T=512, F=64, O=64.
// delta[b,t,f] = (t==0) ? 0 : in[b,t,f]-in[b,t-1,f]
// x = (delta - bn_mean) * (bn_w * rsqrt(bn_var+1e-5)) + bn_b
// enc_o = x * enc_w[o] + enc_b[o]
// LIF scan over o: h = v + (enc_o - v)/2 ; s = (h>=1) ; v = s?0:h
// out[b,o,f,t] = s   (fp32, 0/1)
//
// History: R5 NT stores (-), R6 2x occupancy (null), R7 16KiB runs
// (null), R8 diagnostic: 32 CUs reach 1.66 TB/s but 256 CUs only ~2.6
// TB/s -> cap is a machine-wide function of ADDRESS PATTERN, not CU
// issue/occupancy/stream-count.
//
// R9: FULLY SEQUENTIAL PER-BLOCK STREAMS. All prior schedules wrote
// sparse streams (4-16 KiB fragment, then 128 KiB o-jump -> ~256 B per
// HBM channel per row visit, activate-bound). This version: block owns
// ALL (f,t) of one b (32 elems/thread x 1024 thr), so each o-step
// stores the full 128 KiB [F,T] plane, and consecutive o-planes are
// ADJACENT -> each block is one perfectly sequential stream. o split
// into eighths (silent warm-up recompute, bitwise-identical) -> 256
// blocks = 256 contiguous 1 MiB streams tiling the output = the same
// structure as the 6.5 TB/s harness fill.

#define B_DIM 32
#define T_DIM 512
#define F_DIM 64
#define O_DIM 64

typedef float v4f __attribute__((ext_vector_type(4)));

__global__ __launch_bounds__(1024, 4) void delta_lif_kernel(
    const float* __restrict__ in,     // [B,T,F]
    const float* __restrict__ enc_w,  // [64] (O,1)
    const float* __restrict__ enc_b,  // [64]
    const float* __restrict__ bn_w,   // [1]
    const float* __restrict__ bn_b,   // [1]
    const float* __restrict__ bn_mean,// [1]
    const float* __restrict__ bn_var, // [1]
    float* __restrict__ out)          // [B,O,F,T]
{
#pragma clang fp contract(off)
    // BatchNorm scalars — replicate reference op order exactly.
    const float vpe  = bn_var[0] + 1e-5f;
    const float r    = (float)(1.0 / sqrt((double)vpe));
    const float inv  = bn_w[0] * r;
    const float mean = bn_mean[0];
    const float bnb  = bn_b[0];

    // 256 blocks. XCD swizzle: each XCD gets 32 consecutive vbids
    // = 4 full b-regions = 32 MiB contiguous output.
    const int bid  = blockIdx.x;                  // 0..255
    const int vbid = ((bid & 7) << 5) + (bid >> 3);
    const int b    = vbid >> 3;                   // 0..31
    const int oe   = vbid & 7;                    // o-eighth: stores o in [8*oe, 8*oe+8)

    const int lt = threadIdx.x;                   // 0..1023
    // Thread owns 8 "octet" groups of 4 t-consecutive elements:
    //   group j: f = j*8 + (lt>>7), t0 = (lt&127)*4
    // Store position of group j in the [F,T] plane: f*512 + t0
    //   = j*4096 + lt*4  -> per o-step the block covers the FULL plane,
    //   each thread storing 8 dwordx4 at 16 KiB slot stride.
    const int fsub = lt >> 7;
    const int t0   = (lt & 127) << 2;

    float x[8][4];
    float v[8][4];

    // Compute x for all 8 groups (delta + BN), same fp ops as reference.
#pragma unroll
    for (int j = 0; j < 8; ++j) {
        const int f = (j << 3) + fsub;
        const float* pin = in + b * (T_DIM * F_DIM) + f;
        const float c0 = pin[(t0 + 0) * F_DIM];
        const float c1 = pin[(t0 + 1) * F_DIM];
        const float c2 = pin[(t0 + 2) * F_DIM];
        const float c3 = pin[(t0 + 3) * F_DIM];
        const float p  = (t0 == 0) ? c0 : pin[(t0 - 1) * F_DIM];
        x[j][0] = ((c0 - p)  - mean) * inv + bnb;
        x[j][1] = ((c1 - c0) - mean) * inv + bnb;
        x[j][2] = ((c2 - c1) - mean) * inv + bnb;
        x[j][3] = ((c3 - c2) - mean) * inv + bnb;
        v[j][0] = 0.0f; v[j][1] = 0.0f; v[j][2] = 0.0f; v[j][3] = 0.0f;
    }

    const int o_begin = oe << 3;   // 0,8,...,56

    // Silent warm-up: advance scan state to o_begin (no stores).
    // Identical fp ops in identical order -> bitwise-identical v.
    for (int o = 0; o < o_begin; ++o) {
        const float w  = enc_w[o];
        const float bb = enc_b[o];
#pragma unroll
        for (int j = 0; j < 8; ++j) {
#pragma unroll
            for (int k = 0; k < 4; ++k) {
                const float e = x[j][k] * w + bb;
                const float h = v[j][k] + (e - v[j][k]) * 0.5f;
                v[j][k] = (h >= 1.0f) ? 0.0f : h;
            }
        }
    }

    // Storing phase: 8 o-planes, each 128 KiB contiguous, planes
    // adjacent in memory -> one sequential 1 MiB stream per block.
    // out float-index = (b<<21) + (o<<15) + (j<<12) + lt*4
    float* pbase = out + (b << 21) + (lt << 2);

#pragma unroll
    for (int oi = 0; oi < 8; ++oi) {
        const int o = o_begin + oi;
        const float w  = enc_w[o];
        const float bb = enc_b[o];
        float* pplane = pbase + (o << 15);
#pragma unroll
        for (int j = 0; j < 8; ++j) {
            v4f s;
#pragma unroll
            for (int k = 0; k < 4; ++k) {
                const float e = x[j][k] * w + bb;
                const float h = v[j][k] + (e - v[j][k]) * 0.5f;
                const bool g = (h >= 1.0f);
                ((float*)&s)[k] = g ? 1.0f : 0.0f;
                v[j][k] = g ? 0.0f : h;
            }
            *(v4f*)(pplane + (j << 12)) = s;
        }
    }
}

extern "C" void kernel_launch(void* const* d_in, const int* in_sizes, int n_in,
                              void* d_out, int out_size, void* d_ws, size_t ws_size,
                              hipStream_t stream) {
    const float* in      = (const float*)d_in[0];
    const float* enc_w   = (const float*)d_in[1];
    const float* enc_b   = (const float*)d_in[2];
    const float* bn_w    = (const float*)d_in[3];
    const float* bn_b    = (const float*)d_in[4];
    const float* bn_mean = (const float*)d_in[5];
    const float* bn_var  = (const float*)d_in[6];
    float* out = (float*)d_out;

    // 256 blocks (32 b x 8 o-eighths, XCD-swizzled) x 1024 threads
    delta_lif_kernel<<<dim3(256), dim3(1024), 0, stream>>>(
        in, enc_w, enc_b, bn_w, bn_b, bn_mean, bn_var, out);
}